// Round 15
// baseline (95.060 us; speedup 1.0000x reference)
//
#include <hip/hip_runtime.h>

#define HH 16
#define TT 4096
#define DD 64

typedef __attribute__((ext_vector_type(2))) __fp16 half2r;   // cvt_pkrtz result
typedef __attribute__((ext_vector_type(4))) _Float16 half4;
typedef __attribute__((ext_vector_type(8))) _Float16 half8;
typedef __attribute__((ext_vector_type(4))) float float4v;

// Base (R7..R14): block = 4 waves x 16 q rows = 64 q rows of one head;
// grid 1024 -> 4 blocks/CU; dbuf 64-key K/V LDS tiles; depth-1 prefetch;
// exp2 domain; defer-max (lazy shuffles); lsum via ones-MFMA; setprio;
// XCD swizzle; x32 QK MFMA; conflict-free two-level LDS swizzle (R14: 0 conflicts).
// R15: tile-level software pipeline, 2 barriers/phase:
//   [barA] -> ds_write B(t+1) -> ISSUE(t+2) -> [barB] -> QK(t+1) || softmax(t) -> PV(t)
// QK(t+1) MFMAs overlap softmax(t) VALU (separate pipes). launch_bounds (256,2)
// (VGPR cap 128; <=128 still 16 waves/CU) to carry st across phases w/o spill.
__global__ __launch_bounds__(256, 2) void pa_fwd(
    const float* __restrict__ qg, const float* __restrict__ kg,
    const float* __restrict__ vg, const int* __restrict__ cu,
    float* __restrict__ outg)
{
    __shared__ __align__(16) _Float16 Kl[2][64 * 64];   // [key][d]
    __shared__ __align__(16) _Float16 Vl[2][64 * 64];   // [d][key]

    const int tid  = threadIdx.x;
    const int lane = tid & 63;
    const int wave = tid >> 6;      // 0..3
    const int lr   = lane & 15;
    const int lg   = lane >> 4;

    // XCD swizzle: grid 1024 = 8 XCD x 128 contiguous work items
    const int bswz = ((int)blockIdx.x & 7) * 128 + ((int)blockIdx.x >> 3);
    const int h    = bswz >> 6;            // 0..15
    const int qblk = (bswz & 63) << 6;     // 64 q rows per block
    const int q    = qblk + wave * 16 + lr;

    // per-row segment bounds (searchsorted semantics)
    int s = 0;
    while (cu[s + 1] <= q) ++s;
    const int lo = cu[s], hi = cu[s + 1];

    // block-level staging range
    int sb = 0;
    while (cu[sb + 1] <= qblk) ++sb;
    const int blo = cu[sb];
    while (cu[sb + 1] <= qblk + 63) ++sb;
    const int bhi = cu[sb + 1];

    const int wlo = __shfl(lo, 0);    // wave min key
    const int whi = __shfl(hi, 15);   // wave max key
    const int mlo = __shfl(lo, 15);   // max lo over wave rows
    const int mhi = __shfl(hi, 0);    // min hi over wave rows

    // Q fragment for x32 QK (B operand): lane holds d = ds*32 + lg*8 + j
    const float qscale = 0.125f * 1.44269504088896f;   // 1/sqrt(64) * log2(e)
    const float* qrow = qg + ((size_t)h * TT + q) * DD;
    half8 qf8[2];
#pragma unroll
    for (int ds = 0; ds < 2; ++ds) {
        const float* qp = qrow + ds * 32 + lg * 8;
        float4v a = *(const float4v*)qp;
        float4v b = *(const float4v*)(qp + 4);
        half2r p0 = __builtin_amdgcn_cvt_pkrtz(a[0] * qscale, a[1] * qscale);
        half2r p1 = __builtin_amdgcn_cvt_pkrtz(a[2] * qscale, a[3] * qscale);
        half2r p2 = __builtin_amdgcn_cvt_pkrtz(b[0] * qscale, b[1] * qscale);
        half2r p3 = __builtin_amdgcn_cvt_pkrtz(b[2] * qscale, b[3] * qscale);
        qf8[ds][0] = (_Float16)p0[0]; qf8[ds][1] = (_Float16)p0[1];
        qf8[ds][2] = (_Float16)p1[0]; qf8[ds][3] = (_Float16)p1[1];
        qf8[ds][4] = (_Float16)p2[0]; qf8[ds][5] = (_Float16)p2[1];
        qf8[ds][6] = (_Float16)p3[0]; qf8[ds][7] = (_Float16)p3[1];
    }

    const float* kh_ = kg + (size_t)h * TT * DD;
    const float* vh_ = vg + (size_t)h * TT * DD;

    // ---- staging assignments (R14 layout, measured 0 conflicts) ----
    const int srow = tid >> 2;
    const int sc   = tid & 3;
    const unsigned kwrA = (unsigned)(srow * 128 + (((2 * sc)     ^ (srow & 7)) << 4));
    const unsigned kwrB = (unsigned)(srow * 128 + (((2 * sc + 1) ^ (srow & 7)) << 4));
    const int vd2 = tid & 31;
    const int vko = tid >> 5;
    const int vslot = vko ^ (vd2 & 7);
    const int vhb   = (vd2 >> 3) & 1;
    const unsigned vwA0 = (unsigned)(vd2 * 128 + vslot * 16 + 8 * vhb);
    const unsigned vwA1 = (unsigned)(vd2 * 128 + vslot * 16 + 8 * (1 ^ vhb));
    const unsigned vwB0 = vwA0 + 32 * 128;
    const unsigned vwB1 = vwA1 + 32 * 128;

    // ---- fragment read bases ----
    const unsigned kb0 = (unsigned)(lr * 128 + (((lg)     ^ (lr & 7)) << 4));
    const unsigned kb1 = (unsigned)(lr * 128 + (((4 + lg) ^ (lr & 7)) << 4));
    unsigned vrb[4];
#pragma unroll
    for (int t = 0; t < 4; ++t)
        vrb[t] = (unsigned)(lr * 128 + (((2 * t + (lg >> 1)) ^ (lr & 7)) << 4) +
                            (((lg & 1) ^ ((lr >> 3) & 1)) << 3));

    // constant ones A-fragment for the lsum MFMA
    half4 onesv;
    onesv[0] = onesv[1] = onesv[2] = onesv[3] = (_Float16)1.0f;

    // depth-1 prefetch registers + advancing pointers
    float4v kq[4];
    float vvA[8], vvB[8];
    const int t0k  = blo & ~63;
    const int tend = bhi;
    const float4v* kp = (const float4v*)(kh_ + (size_t)(t0k + srow) * DD + sc * 16);
    const float*   vp = vh_ + (size_t)(t0k + vko * 8) * DD + vd2;

#define ISSUE()                                                                \
    {                                                                          \
        kq[0] = kp[0]; kq[1] = kp[1]; kq[2] = kp[2]; kq[3] = kp[3];            \
        kp += (64 * DD) / 4;                                                   \
        _Pragma("unroll")                                                      \
        for (int c = 0; c < 8; ++c) {                                          \
            vvA[c] = vp[c * DD];                                               \
            vvB[c] = vp[c * DD + 32];                                          \
        }                                                                      \
        vp += 64 * DD;                                                         \
    }

#define PACKW(CUR)                                                             \
    {                                                                          \
        char* Kb = (char*)Kl[CUR];                                             \
        char* Vb = (char*)Vl[CUR];                                             \
        half8 hk0, hk1;                                                        \
        _Pragma("unroll")                                                      \
        for (int i = 0; i < 2; ++i) {                                          \
            half2r a = __builtin_amdgcn_cvt_pkrtz(kq[i][0], kq[i][1]);         \
            half2r b = __builtin_amdgcn_cvt_pkrtz(kq[i][2], kq[i][3]);         \
            hk0[4*i+0] = (_Float16)a[0]; hk0[4*i+1] = (_Float16)a[1];          \
            hk0[4*i+2] = (_Float16)b[0]; hk0[4*i+3] = (_Float16)b[1];          \
            half2r c2 = __builtin_amdgcn_cvt_pkrtz(kq[2+i][0], kq[2+i][1]);    \
            half2r d2 = __builtin_amdgcn_cvt_pkrtz(kq[2+i][2], kq[2+i][3]);    \
            hk1[4*i+0] = (_Float16)c2[0]; hk1[4*i+1] = (_Float16)c2[1];        \
            hk1[4*i+2] = (_Float16)d2[0]; hk1[4*i+3] = (_Float16)d2[1];        \
        }                                                                      \
        *(half8*)(Kb + kwrA) = hk0;                                            \
        *(half8*)(Kb + kwrB) = hk1;                                            \
        half4 uA0, uA1, uB0, uB1;                                              \
        {                                                                      \
            half2r a = __builtin_amdgcn_cvt_pkrtz(vvA[0], vvA[1]);             \
            half2r b = __builtin_amdgcn_cvt_pkrtz(vvA[2], vvA[3]);             \
            uA0[0] = (_Float16)a[0]; uA0[1] = (_Float16)a[1];                  \
            uA0[2] = (_Float16)b[0]; uA0[3] = (_Float16)b[1];                  \
            half2r c2 = __builtin_amdgcn_cvt_pkrtz(vvA[4], vvA[5]);            \
            half2r d2 = __builtin_amdgcn_cvt_pkrtz(vvA[6], vvA[7]);            \
            uA1[0] = (_Float16)c2[0]; uA1[1] = (_Float16)c2[1];                \
            uA1[2] = (_Float16)d2[0]; uA1[3] = (_Float16)d2[1];                \
            half2r e = __builtin_amdgcn_cvt_pkrtz(vvB[0], vvB[1]);             \
            half2r f = __builtin_amdgcn_cvt_pkrtz(vvB[2], vvB[3]);             \
            uB0[0] = (_Float16)e[0]; uB0[1] = (_Float16)e[1];                  \
            uB0[2] = (_Float16)f[0]; uB0[3] = (_Float16)f[1];                  \
            half2r g = __builtin_amdgcn_cvt_pkrtz(vvB[4], vvB[5]);             \
            half2r k2 = __builtin_amdgcn_cvt_pkrtz(vvB[6], vvB[7]);            \
            uB1[0] = (_Float16)g[0]; uB1[1] = (_Float16)g[1];                  \
            uB1[2] = (_Float16)k2[0]; uB1[3] = (_Float16)k2[1];                \
        }                                                                      \
        *(half4*)(Vb + vwA0) = uA0;                                            \
        *(half4*)(Vb + vwA1) = uA1;                                            \
        *(half4*)(Vb + vwB0) = uB0;                                            \
        *(half4*)(Vb + vwB1) = uB1;                                            \
    }

// QK for tile KT from buffer BUF into ST (only when VALID)
#define QKM(KT, BUF, ST, VALID)                                                \
    if (VALID) {                                                               \
        const char* Kb_ = (const char*)Kl[BUF];                                \
        const bool fullv_ = ((KT) >= mlo) && ((KT) + 64 <= mhi);               \
        __builtin_amdgcn_s_setprio(1);                                         \
        _Pragma("unroll")                                                      \
        for (int t = 0; t < 4; ++t) {                                          \
            float4v sa = (float4v){0.f, 0.f, 0.f, 0.f};                        \
            half8 kf0 = *(const half8*)(Kb_ + kb0 + t * 2048);                 \
            half8 kf1 = *(const half8*)(Kb_ + kb1 + t * 2048);                 \
            sa = __builtin_amdgcn_mfma_f32_16x16x32_f16(kf0, qf8[0], sa, 0, 0, 0); \
            sa = __builtin_amdgcn_mfma_f32_16x16x32_f16(kf1, qf8[1], sa, 0, 0, 0); \
            if (fullv_) {                                                      \
                _Pragma("unroll")                                              \
                for (int j = 0; j < 4; ++j) ST[t][j] = sa[j];                  \
            } else {                                                           \
                _Pragma("unroll")                                              \
                for (int j = 0; j < 4; ++j) {                                  \
                    const int key = (KT) + t * 16 + lg * 4 + j;                \
                    ST[t][j] = (key >= lo && key < hi) ? sa[j] : -1e30f;       \
                }                                                              \
            }                                                                  \
        }                                                                      \
        __builtin_amdgcn_s_setprio(0);                                         \
    }

    float4v acc[4];
#pragma unroll
    for (int dt = 0; dt < 4; ++dt) acc[dt] = (float4v){0.f, 0.f, 0.f, 0.f};
    float4v acc_l = (float4v){0.f, 0.f, 0.f, 0.f};
    float m_run = -1e30f;

    // ---- prologue: stage tile t0, issue t0+1, QK(t0) ----
    ISSUE();
    PACKW(0);
    if (t0k + 64 < tend) ISSUE();
    __syncthreads();                       // bar B (prologue)
    float st[4][4];
    bool cv = !(t0k + 64 <= wlo || t0k >= whi);
    QKM(t0k, 0, st, cv);

    int cur = 0;
    for (int kt = t0k; kt < tend; kt += 64) {
        __syncthreads();                   // bar A: prev-phase reads done
        if (kt + 64 < tend) PACKW(cur ^ 1);
        if (kt + 128 < tend) ISSUE();
        __syncthreads();                   // bar B: writes visible

        const bool nxv = (kt + 64 < tend) &&
                         !(kt + 128 <= wlo || kt + 64 >= whi);
        float stn[4][4];
        QKM(kt + 64, cur ^ 1, stn, nxv);   // QK(t+1) — overlaps softmax(t) below

        if (cv) {
            const char* Vb = (const char*)Vl[cur];

            // per-lane max only (no cross-lane in common path)
            float lmax = fmaxf(fmaxf(st[0][0], st[0][1]), fmaxf(st[0][2], st[0][3]));
            lmax = fmaxf(lmax, fmaxf(fmaxf(st[1][0], st[1][1]), fmaxf(st[1][2], st[1][3])));
            lmax = fmaxf(lmax, fmaxf(fmaxf(st[2][0], st[2][1]), fmaxf(st[2][2], st[2][3])));
            lmax = fmaxf(lmax, fmaxf(fmaxf(st[3][0], st[3][1]), fmaxf(st[3][2], st[3][3])));

            if (__any(lmax > m_run + 11.54f)) {
                float tx = fmaxf(lmax, __shfl_xor(lmax, 16));
                tx = fmaxf(tx, __shfl_xor(tx, 32));
                const float mn = fmaxf(m_run, tx);
                const float a  = exp2f(m_run - mn);
#pragma unroll
                for (int dt = 0; dt < 4; ++dt)
#pragma unroll
                    for (int j = 0; j < 4; ++j) acc[dt][j] *= a;
#pragma unroll
                for (int j = 0; j < 4; ++j) acc_l[j] *= a;
                m_run = mn;
            }
            // all-masked rows self-heal at their first real tile (a=0 wipes accs)

            half4 pb[4];
#pragma unroll
            for (int t = 0; t < 4; ++t) {
                float e0 = exp2f(st[t][0] - m_run);
                float e1 = exp2f(st[t][1] - m_run);
                float e2 = exp2f(st[t][2] - m_run);
                float e3 = exp2f(st[t][3] - m_run);
                half2r a = __builtin_amdgcn_cvt_pkrtz(e0, e1);
                half2r b = __builtin_amdgcn_cvt_pkrtz(e2, e3);
                pb[t][0] = (_Float16)a[0]; pb[t][1] = (_Float16)a[1];
                pb[t][2] = (_Float16)b[0]; pb[t][3] = (_Float16)b[1];
            }

            __builtin_amdgcn_s_setprio(1);
#pragma unroll
            for (int t = 0; t < 4; ++t) {
#pragma unroll
                for (int dt = 0; dt < 4; ++dt) {
                    half4 vf = *(const half4*)(Vb + vrb[t] + dt * 2048);
                    acc[dt] = __builtin_amdgcn_mfma_f32_16x16x16f16(vf, pb[t], acc[dt], 0, 0, 0);
                }
                acc_l = __builtin_amdgcn_mfma_f32_16x16x16f16(onesv, pb[t], acc_l, 0, 0, 0);
            }
            __builtin_amdgcn_s_setprio(0);
        }

        if (nxv) {
#pragma unroll
            for (int t = 0; t < 4; ++t)
#pragma unroll
                for (int j = 0; j < 4; ++j) st[t][j] = stn[t][j];
        }
        cv = nxv;
        cur ^= 1;
    }

    const float inv = 1.0f / acc_l[0];   // all acc_l rows equal lsum[q=lr]
    float* orow = outg + ((size_t)h * TT + q) * DD;
#pragma unroll
    for (int dt = 0; dt < 4; ++dt) {
        float4v o;
#pragma unroll
        for (int j = 0; j < 4; ++j) o[j] = acc[dt][j] * inv;
        *(float4v*)(orow + dt * 16 + lg * 4) = o;
    }
#undef ISSUE
#undef PACKW
#undef QKM
}

extern "C" void kernel_launch(void* const* d_in, const int* in_sizes, int n_in,
                              void* d_out, int out_size, void* d_ws, size_t ws_size,
                              hipStream_t stream) {
    const float* q  = (const float*)d_in[0];
    const float* k  = (const float*)d_in[1];
    const float* v  = (const float*)d_in[2];
    const int*   cu = (const int*)d_in[3];
    float* out = (float*)d_out;

    dim3 grid(HH * (TT / 64));   // 1024
    dim3 block(256);
    hipLaunchKernelGGL(pa_fwd, grid, block, 0, stream, q, k, v, cu, out);
}

// Round 16
// 90.161 us; speedup vs baseline: 1.0543x; 1.0543x over previous
//
#include <hip/hip_runtime.h>

#define HH 16
#define TT 4096
#define DD 64

typedef __attribute__((ext_vector_type(2))) __fp16 half2r;   // cvt_pkrtz result
typedef __attribute__((ext_vector_type(4))) _Float16 half4;
typedef __attribute__((ext_vector_type(8))) _Float16 half8;
typedef __attribute__((ext_vector_type(4))) float float4v;

// R16: split-K 8-wave block. Two 4-wave groups over the SAME 64 q rows of one
// head: group 0 = even 64-key tiles, group 1 = odd tiles. Each group stages
// only its own tiles (staging per key unchanged vs R14) into its own dbuf LDS
// (64 KB total). One barrier per 128-key phase. Inner loop = R14 (best, 81us):
// depth-1 prefetch, exp2 domain, defer-max lazy shuffles, lsum via ones-MFMA,
// setprio, x32 QK, conflict-free two-level swizzle (measured 0 conflicts).
// End: merge (m, l, acc) of the two groups through LDS.
// Grid 1024 blocks, 2 resident/CU -> ~512 queue and backfill (tail smoothing);
// longest work-unit halves (22 -> 11 phases).
__global__ __launch_bounds__(512, 4) void pa_fwd(
    const float* __restrict__ qg, const float* __restrict__ kg,
    const float* __restrict__ vg, const int* __restrict__ cu,
    float* __restrict__ outg)
{
    __shared__ __align__(16) _Float16 Kl[2][2][64 * 64];   // [grp][buf][key][d]
    __shared__ __align__(16) _Float16 Vl[2][2][64 * 64];   // [grp][buf][d][key]

    const int tid   = threadIdx.x;
    const int lane  = tid & 63;
    const int wavei = tid >> 6;     // 0..7
    const int grp   = wavei >> 2;   // 0: even tiles, 1: odd tiles
    const int wv    = wavei & 3;    // q sub-block within group
    const int gtid  = tid & 255;    // thread id within group
    const int lr    = lane & 15;
    const int lg    = lane >> 4;

    // XCD swizzle: grid 1024 = 8 XCD x 128 contiguous work items
    const int bswz = ((int)blockIdx.x & 7) * 128 + ((int)blockIdx.x >> 3);
    const int h    = bswz >> 6;            // 0..15
    const int qblk = (bswz & 63) << 6;     // 64 q rows per block
    const int q    = qblk + wv * 16 + lr;

    // per-row segment bounds (searchsorted semantics)
    int s = 0;
    while (cu[s + 1] <= q) ++s;
    const int lo = cu[s], hi = cu[s + 1];

    // block-level staging range
    int sb = 0;
    while (cu[sb + 1] <= qblk) ++sb;
    const int blo = cu[sb];
    while (cu[sb + 1] <= qblk + 63) ++sb;
    const int bhi = cu[sb + 1];

    const int wlo = __shfl(lo, 0);    // wave min key
    const int whi = __shfl(hi, 15);   // wave max key
    const int mlo = __shfl(lo, 15);   // max lo over wave rows
    const int mhi = __shfl(hi, 0);    // min hi over wave rows

    // Q fragment for x32 QK (B operand): lane holds d = ds*32 + lg*8 + j
    const float qscale = 0.125f * 1.44269504088896f;   // 1/sqrt(64) * log2(e)
    const float* qrow = qg + ((size_t)h * TT + q) * DD;
    half8 qf8[2];
#pragma unroll
    for (int ds = 0; ds < 2; ++ds) {
        const float* qp = qrow + ds * 32 + lg * 8;
        float4v a = *(const float4v*)qp;
        float4v b = *(const float4v*)(qp + 4);
        half2r p0 = __builtin_amdgcn_cvt_pkrtz(a[0] * qscale, a[1] * qscale);
        half2r p1 = __builtin_amdgcn_cvt_pkrtz(a[2] * qscale, a[3] * qscale);
        half2r p2 = __builtin_amdgcn_cvt_pkrtz(b[0] * qscale, b[1] * qscale);
        half2r p3 = __builtin_amdgcn_cvt_pkrtz(b[2] * qscale, b[3] * qscale);
        qf8[ds][0] = (_Float16)p0[0]; qf8[ds][1] = (_Float16)p0[1];
        qf8[ds][2] = (_Float16)p1[0]; qf8[ds][3] = (_Float16)p1[1];
        qf8[ds][4] = (_Float16)p2[0]; qf8[ds][5] = (_Float16)p2[1];
        qf8[ds][6] = (_Float16)p3[0]; qf8[ds][7] = (_Float16)p3[1];
    }

    const float* kh_ = kg + (size_t)h * TT * DD;
    const float* vh_ = vg + (size_t)h * TT * DD;

    // ---- staging assignments (within group; R14 layout, 0 conflicts) ----
    const int srow = gtid >> 2;
    const int sc   = gtid & 3;
    const unsigned kwrA = (unsigned)(srow * 128 + (((2 * sc)     ^ (srow & 7)) << 4));
    const unsigned kwrB = (unsigned)(srow * 128 + (((2 * sc + 1) ^ (srow & 7)) << 4));
    const int vd2 = gtid & 31;
    const int vko = gtid >> 5;
    const int vslot = vko ^ (vd2 & 7);
    const int vhb   = (vd2 >> 3) & 1;
    const unsigned vwA0 = (unsigned)(vd2 * 128 + vslot * 16 + 8 * vhb);
    const unsigned vwA1 = (unsigned)(vd2 * 128 + vslot * 16 + 8 * (1 ^ vhb));
    const unsigned vwB0 = vwA0 + 32 * 128;
    const unsigned vwB1 = vwA1 + 32 * 128;

    // ---- fragment read bases ----
    const unsigned kb0 = (unsigned)(lr * 128 + (((lg)     ^ (lr & 7)) << 4));
    const unsigned kb1 = (unsigned)(lr * 128 + (((4 + lg) ^ (lr & 7)) << 4));
    unsigned vrb[4];
#pragma unroll
    for (int t = 0; t < 4; ++t)
        vrb[t] = (unsigned)(lr * 128 + (((2 * t + (lg >> 1)) ^ (lr & 7)) << 4) +
                            (((lg & 1) ^ ((lr >> 3) & 1)) << 3));

    // constant ones A-fragment for the lsum MFMA
    half4 onesv;
    onesv[0] = onesv[1] = onesv[2] = onesv[3] = (_Float16)1.0f;

    // depth-1 prefetch registers + advancing pointers (stride 128 keys)
    float4v kq[4];
    float vvA[8], vvB[8];
    const int t0k = blo & ~63;
    const int t0g = t0k + (grp << 6);
    const float4v* kp = (const float4v*)(kh_ + (size_t)(t0g + srow) * DD + sc * 16);
    const float*   vp = vh_ + (size_t)(t0g + vko * 8) * DD + vd2;

#define ISSUE()                                                                \
    {                                                                          \
        kq[0] = kp[0]; kq[1] = kp[1]; kq[2] = kp[2]; kq[3] = kp[3];            \
        kp += (128 * DD) / 4;                                                  \
        _Pragma("unroll")                                                      \
        for (int c = 0; c < 8; ++c) {                                          \
            vvA[c] = vp[c * DD];                                               \
            vvB[c] = vp[c * DD + 32];                                          \
        }                                                                      \
        vp += 128 * DD;                                                        \
    }

    if (t0g < bhi) ISSUE();

    float4v acc[4];
#pragma unroll
    for (int dt = 0; dt < 4; ++dt) acc[dt] = (float4v){0.f, 0.f, 0.f, 0.f};
    float4v acc_l = (float4v){0.f, 0.f, 0.f, 0.f};   // lsum via ones-MFMA
    float m_run = -1e30f;

    int cur = 0;
    for (int kt = t0k; kt < bhi; kt += 128) {
        const int ktg = kt + (grp << 6);
        const bool vg = ktg < bhi;          // group-uniform

        if (vg) {
            // ---- pack + write LDS [grp][cur] ----
            char* Kb = (char*)Kl[grp][cur];
            char* Vb = (char*)Vl[grp][cur];
            half8 hk0, hk1;
#pragma unroll
            for (int i = 0; i < 2; ++i) {
                half2r a = __builtin_amdgcn_cvt_pkrtz(kq[i][0], kq[i][1]);
                half2r b = __builtin_amdgcn_cvt_pkrtz(kq[i][2], kq[i][3]);
                hk0[4 * i + 0] = (_Float16)a[0]; hk0[4 * i + 1] = (_Float16)a[1];
                hk0[4 * i + 2] = (_Float16)b[0]; hk0[4 * i + 3] = (_Float16)b[1];
                half2r c2 = __builtin_amdgcn_cvt_pkrtz(kq[2 + i][0], kq[2 + i][1]);
                half2r d2 = __builtin_amdgcn_cvt_pkrtz(kq[2 + i][2], kq[2 + i][3]);
                hk1[4 * i + 0] = (_Float16)c2[0]; hk1[4 * i + 1] = (_Float16)c2[1];
                hk1[4 * i + 2] = (_Float16)d2[0]; hk1[4 * i + 3] = (_Float16)d2[1];
            }
            *(half8*)(Kb + kwrA) = hk0;
            *(half8*)(Kb + kwrB) = hk1;

            half4 uA0, uA1, uB0, uB1;
            {
                half2r a = __builtin_amdgcn_cvt_pkrtz(vvA[0], vvA[1]);
                half2r b = __builtin_amdgcn_cvt_pkrtz(vvA[2], vvA[3]);
                uA0[0] = (_Float16)a[0]; uA0[1] = (_Float16)a[1];
                uA0[2] = (_Float16)b[0]; uA0[3] = (_Float16)b[1];
                half2r c2 = __builtin_amdgcn_cvt_pkrtz(vvA[4], vvA[5]);
                half2r d2 = __builtin_amdgcn_cvt_pkrtz(vvA[6], vvA[7]);
                uA1[0] = (_Float16)c2[0]; uA1[1] = (_Float16)c2[1];
                uA1[2] = (_Float16)d2[0]; uA1[3] = (_Float16)d2[1];
                half2r e = __builtin_amdgcn_cvt_pkrtz(vvB[0], vvB[1]);
                half2r f = __builtin_amdgcn_cvt_pkrtz(vvB[2], vvB[3]);
                uB0[0] = (_Float16)e[0]; uB0[1] = (_Float16)e[1];
                uB0[2] = (_Float16)f[0]; uB0[3] = (_Float16)f[1];
                half2r g = __builtin_amdgcn_cvt_pkrtz(vvB[4], vvB[5]);
                half2r k2 = __builtin_amdgcn_cvt_pkrtz(vvB[6], vvB[7]);
                uB1[0] = (_Float16)g[0]; uB1[1] = (_Float16)g[1];
                uB1[2] = (_Float16)k2[0]; uB1[3] = (_Float16)k2[1];
            }
            *(half4*)(Vb + vwA0) = uA0;
            *(half4*)(Vb + vwA1) = uA1;
            *(half4*)(Vb + vwB0) = uB0;
            *(half4*)(Vb + vwB1) = uB1;
        }
        __syncthreads();   // the only barrier per 128-key phase

        if (vg && ktg + 128 < bhi) ISSUE();   // group-uniform prefetch

        if (vg && !(ktg + 64 <= wlo || ktg >= whi)) {
            const char* Kb = (const char*)Kl[grp][cur];
            const char* Vb = (const char*)Vl[grp][cur];

            // ---- QK^T via x32 MFMA: St[key][q], 4 x 16-key quarters ----
            float st[4][4];
            const bool fullv = (ktg >= mlo) && (ktg + 64 <= mhi);  // wave-uniform
            __builtin_amdgcn_s_setprio(1);
#pragma unroll
            for (int t = 0; t < 4; ++t) {
                float4v sa = (float4v){0.f, 0.f, 0.f, 0.f};
                half8 kf0 = *(const half8*)(Kb + kb0 + t * 2048);
                half8 kf1 = *(const half8*)(Kb + kb1 + t * 2048);
                sa = __builtin_amdgcn_mfma_f32_16x16x32_f16(kf0, qf8[0], sa, 0, 0, 0);
                sa = __builtin_amdgcn_mfma_f32_16x16x32_f16(kf1, qf8[1], sa, 0, 0, 0);
                if (fullv) {
#pragma unroll
                    for (int j = 0; j < 4; ++j) st[t][j] = sa[j];
                } else {
#pragma unroll
                    for (int j = 0; j < 4; ++j) {
                        const int key = ktg + t * 16 + lg * 4 + j;
                        st[t][j] = (key >= lo && key < hi) ? sa[j] : -1e30f;
                    }
                }
            }
            __builtin_amdgcn_s_setprio(0);

            // ---- half-hoist V fragments (t=0,1) ----
            half4 vf01[2][4];
#pragma unroll
            for (int t = 0; t < 2; ++t)
#pragma unroll
                for (int dt = 0; dt < 4; ++dt)
                    vf01[t][dt] = *(const half4*)(Vb + vrb[t] + dt * 2048);

            // ---- per-lane max only (no cross-lane in common path) ----
            float lmax = fmaxf(fmaxf(st[0][0], st[0][1]), fmaxf(st[0][2], st[0][3]));
            lmax = fmaxf(lmax, fmaxf(fmaxf(st[1][0], st[1][1]), fmaxf(st[1][2], st[1][3])));
            lmax = fmaxf(lmax, fmaxf(fmaxf(st[2][0], st[2][1]), fmaxf(st[2][2], st[2][3])));
            lmax = fmaxf(lmax, fmaxf(fmaxf(st[3][0], st[3][1]), fmaxf(st[3][2], st[3][3])));

            // defer-max: shuffles + rescale only when some lane exceeds m+8*log2e
            if (__any(lmax > m_run + 11.54f)) {
                float tx = fmaxf(lmax, __shfl_xor(lmax, 16));
                tx = fmaxf(tx, __shfl_xor(tx, 32));
                const float mn = fmaxf(m_run, tx);
                const float a  = exp2f(m_run - mn);
#pragma unroll
                for (int dt = 0; dt < 4; ++dt)
#pragma unroll
                    for (int j = 0; j < 4; ++j) acc[dt][j] *= a;
#pragma unroll
                for (int j = 0; j < 4; ++j) acc_l[j] *= a;
                m_run = mn;
            }
            // all-masked rows self-heal at their first real tile (a=0 wipes accs)

            half4 pb[4];
#pragma unroll
            for (int t = 0; t < 4; ++t) {
                float e0 = exp2f(st[t][0] - m_run);
                float e1 = exp2f(st[t][1] - m_run);
                float e2 = exp2f(st[t][2] - m_run);
                float e3 = exp2f(st[t][3] - m_run);
                half2r a = __builtin_amdgcn_cvt_pkrtz(e0, e1);
                half2r b = __builtin_amdgcn_cvt_pkrtz(e2, e3);
                pb[t][0] = (_Float16)a[0]; pb[t][1] = (_Float16)a[1];
                pb[t][2] = (_Float16)b[0]; pb[t][3] = (_Float16)b[1];
            }

            // ---- PV + lsum ----
            __builtin_amdgcn_s_setprio(1);
#pragma unroll
            for (int t = 0; t < 2; ++t) {
#pragma unroll
                for (int dt = 0; dt < 4; ++dt)
                    acc[dt] = __builtin_amdgcn_mfma_f32_16x16x16f16(vf01[t][dt], pb[t], acc[dt], 0, 0, 0);
                acc_l = __builtin_amdgcn_mfma_f32_16x16x16f16(onesv, pb[t], acc_l, 0, 0, 0);
            }
#pragma unroll
            for (int t = 2; t < 4; ++t) {
#pragma unroll
                for (int dt = 0; dt < 4; ++dt) {
                    half4 vf = *(const half4*)(Vb + vrb[t] + dt * 2048);
                    acc[dt] = __builtin_amdgcn_mfma_f32_16x16x16f16(vf, pb[t], acc[dt], 0, 0, 0);
                }
                acc_l = __builtin_amdgcn_mfma_f32_16x16x16f16(onesv, pb[t], acc_l, 0, 0, 0);
            }
            __builtin_amdgcn_s_setprio(0);
        }
        cur ^= 1;
    }

    // ---- merge: group 1 -> LDS -> group 0 -> global ----
    float* mb = (float*)&Kl[0][0][0];   // 64 rows x 64 f32 acc partials (16 KB)
    float* ml = (float*)&Vl[0][0][0];   // m at [0..63], l at [64..127]

    __syncthreads();   // all tile compute done before overwriting K/V LDS
    if (grp == 1) {
        const int r = wv * 16 + lr;
#pragma unroll
        for (int dt = 0; dt < 4; ++dt)
            *(float4v*)(mb + r * 64 + dt * 16 + lg * 4) = acc[dt];
        if (lg == 0) { ml[r] = m_run; ml[64 + r] = acc_l[0]; }
    }
    __syncthreads();
    if (grp == 0) {
        const int r  = wv * 16 + lr;
        const float mB = ml[r];
        const float lB = ml[64 + r];
        const float M  = fmaxf(m_run, mB);
        const float eA = exp2f(m_run - M);
        const float eB = exp2f(mB - M);
        const float inv = 1.0f / (eA * acc_l[0] + eB * lB);

        float* orow = outg + ((size_t)h * TT + q) * DD;
#pragma unroll
        for (int dt = 0; dt < 4; ++dt) {
            float4v aB = *(const float4v*)(mb + r * 64 + dt * 16 + lg * 4);
            float4v o;
#pragma unroll
            for (int j = 0; j < 4; ++j)
                o[j] = (eA * acc[dt][j] + eB * aB[j]) * inv;
            *(float4v*)(orow + dt * 16 + lg * 4) = o;
        }
    }
#undef ISSUE
}

extern "C" void kernel_launch(void* const* d_in, const int* in_sizes, int n_in,
                              void* d_out, int out_size, void* d_ws, size_t ws_size,
                              hipStream_t stream) {
    const float* q  = (const float*)d_in[0];
    const float* k  = (const float*)d_in[1];
    const float* v  = (const float*)d_in[2];
    const int*   cu = (const int*)d_in[3];
    float* out = (float*)d_out;

    dim3 grid(HH * (TT / 64));   // 1024 blocks of 512 threads
    dim3 block(512);
    hipLaunchKernelGGL(pa_fwd, grid, block, 0, stream, q, k, v, cu, out);
}

// Round 17
// 80.643 us; speedup vs baseline: 1.1788x; 1.1180x over previous
//
#include <hip/hip_runtime.h>

#define HH 16
#define TT 4096
#define DD 64

typedef __attribute__((ext_vector_type(2))) __fp16 half2r;   // cvt_pkrtz result
typedef __attribute__((ext_vector_type(4))) _Float16 half4;
typedef __attribute__((ext_vector_type(8))) _Float16 half8;
typedef __attribute__((ext_vector_type(4))) float float4v;

// ---------------- prep kernel ----------------
// Per (h, 64-key tile) writes to ws:
//   K16[h][tile][key][s] (16B) = f16 K[kt+key][8*(s^(key&7)) .. +8)
//   V16[h][tile][r][s]   (16B) = f16 { V[kt+8e+4rb + 0..3][r], V[kt+8e+4(1-rb) + 0..3][r] }
//      e = s^(r&7), rb = (r>>3)&1
// Under a LINEAR global->LDS copy these reproduce exactly the R14-proven
// swizzled LDS images (K[key][d] one-level, Vt[d][key] two-level swizzle).
__global__ __launch_bounds__(256) void pa_prep(
    const float* __restrict__ kg, const float* __restrict__ vg,
    _Float16* __restrict__ k16, _Float16* __restrict__ v16)
{
    __shared__ __align__(16) float Kf[64 * 68];   // padded: b128 reads 2-way
    __shared__ __align__(16) float Vf[64 * 65];   // padded: scalar col reads spread

    const int bid  = blockIdx.x;
    const int h    = bid >> 6;
    const int tile = bid & 63;
    const int kt   = tile << 6;
    const int t    = threadIdx.x;

    const int row = t >> 2, c4 = (t & 3) * 16;
    const float* ksrc = kg + ((size_t)(h * TT) + kt + row) * DD + c4;
    const float* vsrc = vg + ((size_t)(h * TT) + kt + row) * DD + c4;
#pragma unroll
    for (int i = 0; i < 4; ++i) {
        *(float4v*)&Kf[row * 68 + c4 + i * 4] = *(const float4v*)(ksrc + i * 4);
        *(float4v*)&Vf[row * 65 + c4 + i * 4] = *(const float4v*)(vsrc + i * 4);
    }
    __syncthreads();

    char* kdst = (char*)k16 + ((size_t)h * 64 + tile) * 8192;
    char* vdst = (char*)v16 + ((size_t)h * 64 + tile) * 8192;

#pragma unroll
    for (int rep = 0; rep < 2; ++rep) {
        const int idx = t + rep * 256;
        const int r = idx >> 3, s = idx & 7;
        {   // K slot: source chunk = s ^ (r&7)
            const int sc = s ^ (r & 7);
            float4v a = *(const float4v*)&Kf[r * 68 + sc * 8];
            float4v b = *(const float4v*)&Kf[r * 68 + sc * 8 + 4];
            half2r p0 = __builtin_amdgcn_cvt_pkrtz(a[0], a[1]);
            half2r p1 = __builtin_amdgcn_cvt_pkrtz(a[2], a[3]);
            half2r p2 = __builtin_amdgcn_cvt_pkrtz(b[0], b[1]);
            half2r p3 = __builtin_amdgcn_cvt_pkrtz(b[2], b[3]);
            half8 hk;
            hk[0] = (_Float16)p0[0]; hk[1] = (_Float16)p0[1];
            hk[2] = (_Float16)p1[0]; hk[3] = (_Float16)p1[1];
            hk[4] = (_Float16)p2[0]; hk[5] = (_Float16)p2[1];
            hk[6] = (_Float16)p3[0]; hk[7] = (_Float16)p3[1];
            *(half8*)(kdst + r * 128 + s * 16) = hk;
        }
        {   // V slot: transposed gather with half-swap baked in
            const int e  = s ^ (r & 7);
            const int rb = (r >> 3) & 1;
            const int k0 = 8 * e + 4 * rb;
            const int k1 = 8 * e + 4 * (1 - rb);
            float x0 = Vf[(k0 + 0) * 65 + r];
            float x1 = Vf[(k0 + 1) * 65 + r];
            float x2 = Vf[(k0 + 2) * 65 + r];
            float x3 = Vf[(k0 + 3) * 65 + r];
            float y0 = Vf[(k1 + 0) * 65 + r];
            float y1 = Vf[(k1 + 1) * 65 + r];
            float y2 = Vf[(k1 + 2) * 65 + r];
            float y3 = Vf[(k1 + 3) * 65 + r];
            half2r p0 = __builtin_amdgcn_cvt_pkrtz(x0, x1);
            half2r p1 = __builtin_amdgcn_cvt_pkrtz(x2, x3);
            half2r p2 = __builtin_amdgcn_cvt_pkrtz(y0, y1);
            half2r p3 = __builtin_amdgcn_cvt_pkrtz(y2, y3);
            half8 hv;
            hv[0] = (_Float16)p0[0]; hv[1] = (_Float16)p0[1];
            hv[2] = (_Float16)p1[0]; hv[3] = (_Float16)p1[1];
            hv[4] = (_Float16)p2[0]; hv[5] = (_Float16)p2[1];
            hv[6] = (_Float16)p3[0]; hv[7] = (_Float16)p3[1];
            *(half8*)(vdst + r * 128 + s * 16) = hv;
        }
    }
}

// ---------------- main kernel (R14 structure; staging = linear memcpy) ----------------
__global__ __launch_bounds__(256, 4) void pa_fwd(
    const float* __restrict__ qg, const _Float16* __restrict__ k16,
    const _Float16* __restrict__ v16, const int* __restrict__ cu,
    float* __restrict__ outg)
{
    __shared__ __align__(16) _Float16 Kl[2][64 * 64];   // [key][d] swizzled image
    __shared__ __align__(16) _Float16 Vl[2][64 * 64];   // [d][key] swizzled image

    const int tid  = threadIdx.x;
    const int lane = tid & 63;
    const int wave = tid >> 6;      // 0..3
    const int lr   = lane & 15;
    const int lg   = lane >> 4;

    // XCD swizzle: grid 1024 = 8 XCD x 128 contiguous work items
    const int bswz = ((int)blockIdx.x & 7) * 128 + ((int)blockIdx.x >> 3);
    const int h    = bswz >> 6;            // 0..15
    const int qblk = (bswz & 63) << 6;     // 64 q rows per block
    const int q    = qblk + wave * 16 + lr;

    // per-row segment bounds (searchsorted semantics)
    int s = 0;
    while (cu[s + 1] <= q) ++s;
    const int lo = cu[s], hi = cu[s + 1];

    // block-level staging range
    int sb = 0;
    while (cu[sb + 1] <= qblk) ++sb;
    const int blo = cu[sb];
    while (cu[sb + 1] <= qblk + 63) ++sb;
    const int bhi = cu[sb + 1];

    const int wlo = __shfl(lo, 0);    // wave min key
    const int whi = __shfl(hi, 15);   // wave max key
    const int mlo = __shfl(lo, 15);   // max lo over wave rows
    const int mhi = __shfl(hi, 0);    // min hi over wave rows

    // Q fragment for x32 QK (B operand), exp2 domain
    const float qscale = 0.125f * 1.44269504088896f;
    const float* qrow = qg + ((size_t)h * TT + q) * DD;
    half8 qf8[2];
#pragma unroll
    for (int ds = 0; ds < 2; ++ds) {
        const float* qp = qrow + ds * 32 + lg * 8;
        float4v a = *(const float4v*)qp;
        float4v b = *(const float4v*)(qp + 4);
        half2r p0 = __builtin_amdgcn_cvt_pkrtz(a[0] * qscale, a[1] * qscale);
        half2r p1 = __builtin_amdgcn_cvt_pkrtz(a[2] * qscale, a[3] * qscale);
        half2r p2 = __builtin_amdgcn_cvt_pkrtz(b[0] * qscale, b[1] * qscale);
        half2r p3 = __builtin_amdgcn_cvt_pkrtz(b[2] * qscale, b[3] * qscale);
        qf8[ds][0] = (_Float16)p0[0]; qf8[ds][1] = (_Float16)p0[1];
        qf8[ds][2] = (_Float16)p1[0]; qf8[ds][3] = (_Float16)p1[1];
        qf8[ds][4] = (_Float16)p2[0]; qf8[ds][5] = (_Float16)p2[1];
        qf8[ds][6] = (_Float16)p3[0]; qf8[ds][7] = (_Float16)p3[1];
    }

    // ---- staging: pure linear copy; wave w covers bytes [w*2048, w*2048+2048) ----
    const unsigned soff0 = (unsigned)(wave * 2048 + lane * 16);
    const unsigned soff1 = soff0 + 1024;

    // ---- fragment read bases (R14-proven swizzled reads) ----
    const unsigned kb0 = (unsigned)(lr * 128 + (((lg)     ^ (lr & 7)) << 4));
    const unsigned kb1 = (unsigned)(lr * 128 + (((4 + lg) ^ (lr & 7)) << 4));
    unsigned vrb[4];
#pragma unroll
    for (int t = 0; t < 4; ++t)
        vrb[t] = (unsigned)(lr * 128 + (((2 * t + (lg >> 1)) ^ (lr & 7)) << 4) +
                            (((lg & 1) ^ ((lr >> 3) & 1)) << 3));

    half4 onesv;
    onesv[0] = onesv[1] = onesv[2] = onesv[3] = (_Float16)1.0f;

    // depth-1 prefetch registers + advancing byte pointers
    half8 kr0, kr1, vr0, vr1;
    const int t0k = blo & ~63;
    const char* gk = (const char*)k16 + (size_t)h * 524288 + (size_t)t0k * 128 + soff0;
    const char* gv = (const char*)v16 + (size_t)h * 524288 + (size_t)t0k * 128 + soff0;

#define ISSUE()                                                                \
    {                                                                          \
        kr0 = *(const half8*)gk; kr1 = *(const half8*)(gk + 1024);             \
        vr0 = *(const half8*)gv; vr1 = *(const half8*)(gv + 1024);             \
        gk += 8192; gv += 8192;                                                \
    }

    ISSUE();

    float4v acc[4];
#pragma unroll
    for (int dt = 0; dt < 4; ++dt) acc[dt] = (float4v){0.f, 0.f, 0.f, 0.f};
    float4v acc_l = (float4v){0.f, 0.f, 0.f, 0.f};   // lsum via ones-MFMA
    float m_run = -1e30f;

    int cur = 0;
    for (int kt = t0k; kt < bhi; kt += 64) {
        // ---- write LDS buf[cur] from prefetch regs (4 x b128, linear) ----
        {
            char* Kb = (char*)Kl[cur];
            char* Vb = (char*)Vl[cur];
            *(half8*)(Kb + soff0) = kr0;
            *(half8*)(Kb + soff1) = kr1;
            *(half8*)(Vb + soff0) = vr0;
            *(half8*)(Vb + soff1) = vr1;
        }
        __syncthreads();   // the only barrier per tile

        if (kt + 64 < bhi) ISSUE();   // block-uniform; lands during compute

        if (!(kt + 64 <= wlo || kt >= whi)) {
            const char* Kb = (const char*)Kl[cur];
            const char* Vb = (const char*)Vl[cur];

            // ---- QK^T via x32 MFMA: St[key][q], 4 x 16-key quarters ----
            float st[4][4];
            const bool fullv = (kt >= mlo) && (kt + 64 <= mhi);  // wave-uniform
            __builtin_amdgcn_s_setprio(1);
#pragma unroll
            for (int t = 0; t < 4; ++t) {
                float4v sa = (float4v){0.f, 0.f, 0.f, 0.f};
                half8 kf0 = *(const half8*)(Kb + kb0 + t * 2048);
                half8 kf1 = *(const half8*)(Kb + kb1 + t * 2048);
                sa = __builtin_amdgcn_mfma_f32_16x16x32_f16(kf0, qf8[0], sa, 0, 0, 0);
                sa = __builtin_amdgcn_mfma_f32_16x16x32_f16(kf1, qf8[1], sa, 0, 0, 0);
                if (fullv) {
#pragma unroll
                    for (int j = 0; j < 4; ++j) st[t][j] = sa[j];
                } else {
#pragma unroll
                    for (int j = 0; j < 4; ++j) {
                        const int key = kt + t * 16 + lg * 4 + j;
                        st[t][j] = (key >= lo && key < hi) ? sa[j] : -1e30f;
                    }
                }
            }
            __builtin_amdgcn_s_setprio(0);

            // ---- half-hoist V fragments (t=0,1) ----
            half4 vf01[2][4];
#pragma unroll
            for (int t = 0; t < 2; ++t)
#pragma unroll
                for (int dt = 0; dt < 4; ++dt)
                    vf01[t][dt] = *(const half4*)(Vb + vrb[t] + dt * 2048);

            // ---- per-lane max only (no cross-lane in common path) ----
            float lmax = fmaxf(fmaxf(st[0][0], st[0][1]), fmaxf(st[0][2], st[0][3]));
            lmax = fmaxf(lmax, fmaxf(fmaxf(st[1][0], st[1][1]), fmaxf(st[1][2], st[1][3])));
            lmax = fmaxf(lmax, fmaxf(fmaxf(st[2][0], st[2][1]), fmaxf(st[2][2], st[2][3])));
            lmax = fmaxf(lmax, fmaxf(fmaxf(st[3][0], st[3][1]), fmaxf(st[3][2], st[3][3])));

            if (__any(lmax > m_run + 11.54f)) {
                float tx = fmaxf(lmax, __shfl_xor(lmax, 16));
                tx = fmaxf(tx, __shfl_xor(tx, 32));
                const float mn = fmaxf(m_run, tx);
                const float a  = exp2f(m_run - mn);
#pragma unroll
                for (int dt = 0; dt < 4; ++dt)
#pragma unroll
                    for (int j = 0; j < 4; ++j) acc[dt][j] *= a;
#pragma unroll
                for (int j = 0; j < 4; ++j) acc_l[j] *= a;
                m_run = mn;
            }
            // all-masked rows self-heal at their first real tile (a=0 wipes accs)

            half4 pb[4];
#pragma unroll
            for (int t = 0; t < 4; ++t) {
                float e0 = exp2f(st[t][0] - m_run);
                float e1 = exp2f(st[t][1] - m_run);
                float e2 = exp2f(st[t][2] - m_run);
                float e3 = exp2f(st[t][3] - m_run);
                half2r a = __builtin_amdgcn_cvt_pkrtz(e0, e1);
                half2r b = __builtin_amdgcn_cvt_pkrtz(e2, e3);
                pb[t][0] = (_Float16)a[0]; pb[t][1] = (_Float16)a[1];
                pb[t][2] = (_Float16)b[0]; pb[t][3] = (_Float16)b[1];
            }

            // ---- PV + lsum ----
            __builtin_amdgcn_s_setprio(1);
#pragma unroll
            for (int t = 0; t < 2; ++t) {
#pragma unroll
                for (int dt = 0; dt < 4; ++dt)
                    acc[dt] = __builtin_amdgcn_mfma_f32_16x16x16f16(vf01[t][dt], pb[t], acc[dt], 0, 0, 0);
                acc_l = __builtin_amdgcn_mfma_f32_16x16x16f16(onesv, pb[t], acc_l, 0, 0, 0);
            }
#pragma unroll
            for (int t = 2; t < 4; ++t) {
#pragma unroll
                for (int dt = 0; dt < 4; ++dt) {
                    half4 vf = *(const half4*)(Vb + vrb[t] + dt * 2048);
                    acc[dt] = __builtin_amdgcn_mfma_f32_16x16x16f16(vf, pb[t], acc[dt], 0, 0, 0);
                }
                acc_l = __builtin_amdgcn_mfma_f32_16x16x16f16(onesv, pb[t], acc_l, 0, 0, 0);
            }
            __builtin_amdgcn_s_setprio(0);
        }
        cur ^= 1;
    }

    const float inv = 1.0f / acc_l[0];   // all acc_l rows equal lsum[q=lr]
    float* orow = outg + ((size_t)h * TT + q) * DD;
#pragma unroll
    for (int dt = 0; dt < 4; ++dt) {
        float4v o;
#pragma unroll
        for (int j = 0; j < 4; ++j) o[j] = acc[dt][j] * inv;
        *(float4v*)(orow + dt * 16 + lg * 4) = o;
    }
#undef ISSUE
}

extern "C" void kernel_launch(void* const* d_in, const int* in_sizes, int n_in,
                              void* d_out, int out_size, void* d_ws, size_t ws_size,
                              hipStream_t stream) {
    const float* q  = (const float*)d_in[0];
    const float* k  = (const float*)d_in[1];
    const float* v  = (const float*)d_in[2];
    const int*   cu = (const int*)d_in[3];
    float* out = (float*)d_out;

    _Float16* k16 = (_Float16*)d_ws;                          // 8.39 MB
    _Float16* v16 = (_Float16*)((char*)d_ws + 8388608);       // 8.39 MB

    dim3 pgrid(HH * 64), pblock(256);
    hipLaunchKernelGGL(pa_prep, pgrid, pblock, 0, stream, k, v, k16, v16);

    dim3 grid(HH * (TT / 64)), block(256);   // 1024 x 256
    hipLaunchKernelGGL(pa_fwd, grid, block, 0, stream, q, k16, v16, cu, out);
}